// Round 9
// baseline (15.153 us; speedup 1.0000x reference)
//
#include <hip/hip_runtime.h>
#include <hip/hip_bf16.h>
#include <math.h>

// Shapes fixed by reference: B=2, L=385, C=128, N=384, 2C=256
// Verified identity (rounds 0-7 all passed):
//   out[b,1+i,c] = b[c] + sum_{kk=0}^{255} (coefA[b,kk]*F[b,i,kk&127] + coefB[b,kk]) * W[c,kk]
//     coefA[kk] = -s_kk (kk<128) | gamma[kk] (kk>=128)
//     coefB[kk] = s_kk*M_kk + beta[kk] (kk<128) | beta[kk] (kk>=128)
//     s_k = gamma[k]/sqrt(var_j F[:,k]+eps);  M_k = sum_j softmax_j(s_k F[j,k]) F[j,k]
// Wave-private stats: wave w owns channels 8w..8w+7. Lane l = (rr=l>>1, half=l&1)
// holds rows rr+32*((rt+r)%12) for channels 8w+half*4..+3 -> v[0] is the block's
// own tile row (static index). shfl_xor butterfly (masks 2..32) reduces over rr
// leaving totals in EVERY lane -> no LDS partials, no broadcast, no finalize
// stage. One barrier total (As/Wb staging -> MFMA).

#define B_   2
#define L_   385
#define C_   128
#define N_   384
#define LC_  (L_ * C_)
#define EPS_ 1e-5f
#define RB_  12
#define NTHR_ 1024
#define LOG2E_ 1.44269504088896340736f

typedef short short8 __attribute__((ext_vector_type(8)));
typedef float f32x4 __attribute__((ext_vector_type(4)));

union V16 { ushort us[8]; uint4 v4; };
union V8u { ushort us[4]; uint2 u2; };

__device__ inline ushort f2bf(float f) {
  __hip_bfloat16 hb = __float2bfloat16(f);   // hw RNE
  return __builtin_bit_cast(ushort, hb);
}

__device__ inline float fast_exp2(float xv) {
#if __has_builtin(__builtin_amdgcn_exp2f)
  return __builtin_amdgcn_exp2f(xv);
#else
  float r;
  asm("v_exp_f32 %0, %1" : "=v"(r) : "v"(xv));
  return r;
#endif
}

__global__ __launch_bounds__(NTHR_, 1) void lnp_kernel(
    const float* __restrict__ x, const float* __restrict__ gamma,
    const float* __restrict__ beta, const float* __restrict__ W,
    const float* __restrict__ bvec, float* __restrict__ out) {
  __shared__ __align__(16) ushort Wb[128 * 256];  // [c][kk^((c&7)<<3)] bf16
  __shared__ __align__(16) ushort As[32 * 256];   // [i][kk^((i&7)<<3)] bf16

  const int blk = blockIdx.x;
  const int b   = blk / RB_;
  const int rt  = blk % RB_;
  const int r0  = rt * 32;
  const int t   = threadIdx.x;
  const int w   = t >> 6;
  const int l   = t & 63;
  const int half = l & 1;
  const int rr  = l >> 1;          // row-within-tile this lane owns
  const int ch4 = 8 * w + half * 4;  // 4 owned channels (lower half)

  const float* Fb = x + (size_t)b * LC_ + C_;   // F[j][c] = Fb[j*128+c]

  // MFMA tile indices
  const int l16 = l & 15, lg = l >> 4, tn = w & 7, tm = w >> 3;
  const int bc = tn * 16 + l16;    // output col
  const int ar = tm * 16 + l16;    // A row (local)

  // ================= phase 0: issue ALL global loads =================
  f32x4 v[12];   // v[r] = F[rr + 32*((rt+r)%12)][ch4..ch4+3]; v[0] = tile row
#pragma unroll
  for (int r = 0; r < 12; ++r) {
    int jr = rt + r; if (jr >= RB_) jr -= RB_;
    v[r] = *(const f32x4*)(Fb + (size_t)(rr + 32 * jr) * C_ + ch4);
  }
  const f32x4 g_lo = *(const f32x4*)&gamma[ch4];
  const f32x4 b_lo = *(const f32x4*)&beta[ch4];
  const f32x4 g_up = *(const f32x4*)&gamma[128 + ch4];
  const f32x4 b_up = *(const f32x4*)&beta[128 + ch4];
  const int cW = t >> 3, kb = (t & 7) * 32, swzW = (cW & 7) << 3;
  f32x4 wv[8];
#pragma unroll
  for (int q = 0; q < 8; ++q)
    wv[q] = *(const f32x4*)&W[cW * 256 + kb + q * 4];
  const float bb = bvec[bc];

  // cls-token passthrough
  if (rt == 0 && t < C_)
    out[(size_t)b * LC_ + t] = x[(size_t)b * LC_ + t];

  // ================= stats: sum / sumsq over 12 owned rows =================
  f32x4 s1 = v[0], s2 = v[0] * v[0];
#pragma unroll
  for (int r = 1; r < 12; ++r) { s1 += v[r]; s2 += v[r] * v[r]; }
  // butterfly over rr (masks 2..32 keep bit0 = half): every lane gets totals
#pragma unroll
  for (int m = 2; m <= 32; m <<= 1) {
#pragma unroll
    for (int j = 0; j < 4; ++j) {
      s1[j] += __shfl_xor(s1[j], m);
      s2[j] += __shfl_xor(s2[j], m);
    }
  }

  // ---- Wb convert (independent of stats; fills shfl-latency gaps) ----
#pragma unroll
  for (int q = 0; q < 4; ++q) {
    V16 pk;
#pragma unroll
    for (int j = 0; j < 4; ++j) {
      pk.us[j]     = f2bf(wv[2 * q][j]);
      pk.us[4 + j] = f2bf(wv[2 * q + 1][j]);
    }
    *(uint4*)&Wb[cW * 256 + ((kb + q * 8) ^ swzW)] = pk.v4;
  }

  // ---- finalize s (every lane, its own 4 channels; uniform per lane-pair) ----
  const f32x4 mean = s1 * (1.0f / N_);
  const f32x4 varr = s2 * (1.0f / N_) - mean * mean;
  f32x4 s, sl, sh;
#pragma unroll
  for (int j = 0; j < 4; ++j) {
    const float vv = fmaxf(varr[j], 0.0f);
    s[j]  = g_lo[j] * rsqrtf(vv + EPS_);
    sl[j] = s[j] * LOG2E_;
    sh[j] = sl[j] * mean[j];
  }

  // ================= exp pass (pure regs) =================
  f32x4 se = {0.f, 0.f, 0.f, 0.f}, sf = {0.f, 0.f, 0.f, 0.f};
#pragma unroll
  for (int r = 0; r < 12; ++r) {
#pragma unroll
    for (int j = 0; j < 4; ++j) {
      const float e = fast_exp2(fmaf(sl[j], v[r][j], -sh[j]));
      se[j] += e;
      sf[j] = fmaf(e, v[r][j], sf[j]);
    }
  }
#pragma unroll
  for (int m = 2; m <= 32; m <<= 1) {
#pragma unroll
    for (int j = 0; j < 4; ++j) {
      se[j] += __shfl_xor(se[j], m);
      sf[j] += __shfl_xor(sf[j], m);
    }
  }

  // ================= As build from v[0] (already in regs) =================
  {
    const int swzA = (rr & 7) << 3;
    V8u lo, up;
#pragma unroll
    for (int j = 0; j < 4; ++j) {
      const float fac = fmaf(s[j], sf[j] / se[j], b_lo[j]);  // s*M + beta
      lo.us[j] = f2bf(fmaf(-s[j], v[0][j], fac));            // -s*F + fac
      up.us[j] = f2bf(fmaf(g_up[j], v[0][j], b_up[j]));      // g*F + beta
    }
    *(uint2*)&As[rr * 256 + (ch4 ^ swzA)] = lo.u2;
    *(uint2*)&As[rr * 256 + ((128 + ch4) ^ swzA)] = up.u2;
  }
  __syncthreads();   // the ONLY barrier

  // ================= MFMA: 16 waves x one 16x16 tile, K=256 =================
  {
    const int abase = ar * 256, aswz = (ar & 7) << 3;
    const int bbase = bc * 256, bswz = (bc & 7) << 3;
    f32x4 acc = {0.f, 0.f, 0.f, 0.f};
#pragma unroll
    for (int kt = 0; kt < 8; ++kt) {
      const int kk = kt * 32 + lg * 8;
      const short8 av = *(const short8*)&As[abase + (kk ^ aswz)];
      const short8 bv = *(const short8*)&Wb[bbase + (kk ^ bswz)];
      acc = __builtin_amdgcn_mfma_f32_16x16x32_bf16(av, bv, acc, 0, 0, 0);
    }
    float* ob = out + (size_t)b * LC_;
#pragma unroll
    for (int r = 0; r < 4; ++r) {
      const int m = tm * 16 + lg * 4 + r;
      ob[(size_t)(1 + r0 + m) * C_ + bc] = acc[r] + bb;
    }
  }
}

extern "C" void kernel_launch(void* const* d_in, const int* in_sizes, int n_in,
                              void* d_out, int out_size, void* d_ws, size_t ws_size,
                              hipStream_t stream) {
  const float* x     = (const float*)d_in[0];
  const float* gamma = (const float*)d_in[1];
  const float* beta  = (const float*)d_in[2];
  const float* W     = (const float*)d_in[3];
  const float* bvec  = (const float*)d_in[4];
  float* out = (float*)d_out;

  lnp_kernel<<<B_ * RB_, NTHR_, 0, stream>>>(x, gamma, beta, W, bvec, out);
}